// Round 12
// baseline (405.821 us; speedup 1.0000x reference)
//
#include <hip/hip_runtime.h>

#define NN 50000
#define NE 800000

// ---- bf16 helpers (manual RNE; values are finite) --------------------------
__device__ inline unsigned short f2bf(float f) {
    unsigned u = __float_as_uint(f);
    unsigned r = (u + 0x7FFFu + ((u >> 16) & 1u)) >> 16;
    return (unsigned short)r;
}
__device__ inline float bf2f(unsigned short h) {
    return __uint_as_float(((unsigned)h) << 16);
}

// ---- fused: degree/cursor atomics + proj0 (feat @ W0, UNscaled) ------------
// Degree phase is memory-side atomic-RMW bound: 1.6M RMWs x ~33B = 52.9MB of
// WRITE_SIZE at ~650GB/s = ~80us floor. Proven structural: in-flight depth
// (r3), nt hints (r9), per-XCD workgroup-scope shards (r10: WRITE_SIZE
// byte-identical) all failed to move it. proj0 rides along on the otherwise-
// idle CUs. Role by blockIdx: bid%3==0 -> degree block (391 blocks, 2048
// edges, 8/thread), else proj tile (782). dout_is scaling lives in gather-0
// ((s*x)@W == s*(x@W)).
__global__ __launch_bounds__(256) void fused_build_proj0_kernel(
    const float* __restrict__ A,          // feat, lda=256
    const float* __restrict__ W,          // 256x64 row-major
    unsigned short* __restrict__ Xh,      // bf16 out, 50000x64
    const int* __restrict__ src, const int* __restrict__ dst,
    int* __restrict__ dout_cnt, int* __restrict__ cursor,
    int* __restrict__ epos) {
    __shared__ float sAT[64 * 68];  // [k][row], pitch 68
    __shared__ float sW[64 * 64];   // [k][col]

    const int bid = blockIdx.x;
    if (bid % 3 == 0) {
        // ---- degree / CSR-slot role: 8 edges per thread, atomics unrolled --
        const int d = bid / 3;                  // 0..390
        const int e0 = d * 2048 + threadIdx.x;  // stride-256 over 8 slots
        int s[8], dn[8], p[8];
#pragma unroll
        for (int j = 0; j < 8; ++j) {
            int e = e0 + j * 256;
            if (e < NE) { s[j] = src[e]; dn[j] = dst[e]; } else dn[j] = -1;
        }
#pragma unroll
        for (int j = 0; j < 8; ++j)
            if (dn[j] >= 0) p[j] = atomicAdd(&cursor[dn[j]], 1);
#pragma unroll
        for (int j = 0; j < 8; ++j)
            if (dn[j] >= 0) atomicAdd(&dout_cnt[s[j]], 1);
#pragma unroll
        for (int j = 0; j < 8; ++j) {
            int e = e0 + j * 256;
            if (e < NE) epos[e] = p[j];
        }
        return;
    }

    // ---- proj role: 64x64 tile of X = feat @ W0 (no scale) ----
    const int p = bid - bid / 3 - 1;          // tile id 0..781
    constexpr int lda = 256;
    constexpr int KC = 64;
    constexpr int NCHUNK = 4;                 // K = 256
    float acc[4][4] = {};

    const int t = threadIdx.x;
    const int tx = t & 15;
    const int ty = t >> 4;
    const int row0 = p * 64;

    const int srow = t & 63;
    const int f0 = t >> 6;
    int grow = row0 + srow;
    if (grow > NN - 1) grow = NN - 1;         // clamp: loads always in-bounds
    const float* arow = A + (size_t)grow * lda;

    for (int kc = 0; kc < NCHUNK; ++kc) {
#pragma unroll
        for (int it = 0; it < 4; ++it) {
            int k = (f0 + it * 4) * 4;
            float4 a4 = *reinterpret_cast<const float4*>(arow + kc * KC + k);
            sAT[(k + 0) * 68 + srow] = a4.x;
            sAT[(k + 1) * 68 + srow] = a4.y;
            sAT[(k + 2) * 68 + srow] = a4.z;
            sAT[(k + 3) * 68 + srow] = a4.w;
        }
        {
            const float4* wsrc = reinterpret_cast<const float4*>(W + (size_t)kc * KC * 64);
            float4* wdst = reinterpret_cast<float4*>(sW);
#pragma unroll
            for (int it = 0; it < 4; ++it) wdst[t + it * 256] = wsrc[t + it * 256];
        }
        __syncthreads();
#pragma unroll 8
        for (int k = 0; k < KC; ++k) {
            float4 av = *reinterpret_cast<const float4*>(&sAT[k * 68 + ty * 4]);
            float4 wv = *reinterpret_cast<const float4*>(&sW[k * 64 + tx * 4]);
            acc[0][0] = fmaf(av.x, wv.x, acc[0][0]);
            acc[0][1] = fmaf(av.x, wv.y, acc[0][1]);
            acc[0][2] = fmaf(av.x, wv.z, acc[0][2]);
            acc[0][3] = fmaf(av.x, wv.w, acc[0][3]);
            acc[1][0] = fmaf(av.y, wv.x, acc[1][0]);
            acc[1][1] = fmaf(av.y, wv.y, acc[1][1]);
            acc[1][2] = fmaf(av.y, wv.z, acc[1][2]);
            acc[1][3] = fmaf(av.y, wv.w, acc[1][3]);
            acc[2][0] = fmaf(av.z, wv.x, acc[2][0]);
            acc[2][1] = fmaf(av.z, wv.y, acc[2][1]);
            acc[2][2] = fmaf(av.z, wv.z, acc[2][2]);
            acc[2][3] = fmaf(av.z, wv.w, acc[2][3]);
            acc[3][0] = fmaf(av.w, wv.x, acc[3][0]);
            acc[3][1] = fmaf(av.w, wv.y, acc[3][1]);
            acc[3][2] = fmaf(av.w, wv.z, acc[3][2]);
            acc[3][3] = fmaf(av.w, wv.w, acc[3][3]);
        }
        __syncthreads();
    }
#pragma unroll
    for (int i = 0; i < 4; ++i) {
        int r = row0 + ty * 4 + i;
        if (r < NN) {
            ushort4 h = {f2bf(acc[i][0]), f2bf(acc[i][1]), f2bf(acc[i][2]), f2bf(acc[i][3])};
            *reinterpret_cast<ushort4*>(Xh + (size_t)r * 64 + tx * 4) = h;
        }
    }
}

// ---- scan helpers ----------------------------------------------------------
__device__ inline int wave_incl_scan(int v) {
    int lane = threadIdx.x & 63;
#pragma unroll
    for (int off = 1; off < 64; off <<= 1) {
        int t = __shfl_up(v, off, 64);
        if (lane >= off) v += t;
    }
    return v;
}

// A: per-block local exclusive scan of in-degree; block totals to partials
__global__ void scan_local_kernel(const int* __restrict__ din_cnt,
                                  int* __restrict__ row_start,
                                  int* __restrict__ partials) {
    __shared__ int wsum[4];
    int i = blockIdx.x * 256 + threadIdx.x;
    int v = (i < NN) ? din_cnt[i] : 0;
    int lane = threadIdx.x & 63, wid = threadIdx.x >> 6;
    int incl = wave_incl_scan(v);
    if (lane == 63) wsum[wid] = incl;
    __syncthreads();
    if (threadIdx.x == 0) {
        int s = 0;
        for (int w = 0; w < 4; ++w) { int t = wsum[w]; wsum[w] = s; s += t; }
        partials[blockIdx.x] = s;
    }
    __syncthreads();
    if (i < NN) row_start[i] = incl - v + wsum[wid];
}

// B: single-block exclusive scan of the 196 partials (in place)
__global__ void scan_partials_kernel(int* __restrict__ partials, int nparts,
                                     int* __restrict__ row_start) {
    __shared__ int wsum[4];
    int v = (threadIdx.x < nparts) ? partials[threadIdx.x] : 0;
    int lane = threadIdx.x & 63, wid = threadIdx.x >> 6;
    int incl = wave_incl_scan(v);
    if (lane == 63) wsum[wid] = incl;
    __syncthreads();
    if (threadIdx.x == 0) {
        int s = 0;
        for (int w = 0; w < 4; ++w) { int t = wsum[w]; wsum[w] = s; s += t; }
        row_start[NN] = NE;  // total in-degree == edge count
    }
    __syncthreads();
    if (threadIdx.x < nparts) partials[threadIdx.x] = incl - v + wsum[wid];
}

// C: add block offsets + emit rsqrt normalizers (fused, one pass over nodes)
__global__ void scan_add_norm_kernel(int* __restrict__ row_start, const int* __restrict__ partials,
                                     const int* __restrict__ dout_cnt, const int* __restrict__ din_cnt,
                                     float* __restrict__ dout_is, float* __restrict__ din_is) {
    int i = blockIdx.x * 256 + threadIdx.x;
    if (i < NN) {
        row_start[i] += partials[blockIdx.x];
        dout_is[i] = rsqrtf(fmaxf((float)dout_cnt[i], 1.0f));
        din_is[i]  = rsqrtf(fmaxf((float)din_cnt[i], 1.0f));
    }
}

// fill CSR: atomic-free scattered write using precomputed slots
__global__ void csr_fill_kernel(const int* __restrict__ src, const int* __restrict__ dst,
                                const int* __restrict__ row_start, const int* __restrict__ epos,
                                int* __restrict__ csr_src) {
    int e = blockIdx.x * 256 + threadIdx.x;
    if (e < NE) csr_src[row_start[dst[e]] + epos[e]] = src[e];
}

// ---- X = rowscale(A) @ W, register-blocked 64x64 tile (tail proj only) -----
template <int K, bool OUT_BF16>
__global__ __launch_bounds__(256) void proj_kernel(
    const float* __restrict__ A, int lda,
    const float* __restrict__ W,   // K x 64, row-major
    const float* __restrict__ scale,
    void* __restrict__ Xout) {
    constexpr int KC = 64;
    constexpr int NCHUNK = K / KC;
    __shared__ float sAT[KC * 68];  // [k][row], pitch 68
    __shared__ float sW[KC * 64];   // [k][col]
    float acc[4][4] = {};

    const int t = threadIdx.x;
    const int tx = t & 15;          // col group: cols 4*tx..4*tx+3
    const int ty = t >> 4;          // row group: rows 4*ty..4*ty+3
    const int row0 = blockIdx.x * 64;

    const int srow = t & 63;        // staging: one row per lane
    const int f0 = t >> 6;          // staging float4-col base (0..3)
    int grow = row0 + srow;
    if (grow > NN - 1) grow = NN - 1;   // clamp: loads always in-bounds
    const float* arow = A + (size_t)grow * lda;

    for (int kc = 0; kc < NCHUNK; ++kc) {
#pragma unroll
        for (int it = 0; it < 4; ++it) {
            int k = (f0 + it * 4) * 4;
            float4 a4 = *reinterpret_cast<const float4*>(arow + kc * KC + k);
            sAT[(k + 0) * 68 + srow] = a4.x;
            sAT[(k + 1) * 68 + srow] = a4.y;
            sAT[(k + 2) * 68 + srow] = a4.z;
            sAT[(k + 3) * 68 + srow] = a4.w;
        }
        {
            const float4* wsrc = reinterpret_cast<const float4*>(W + (size_t)kc * KC * 64);
            float4* wdst = reinterpret_cast<float4*>(sW);
#pragma unroll
            for (int it = 0; it < 4; ++it) wdst[t + it * 256] = wsrc[t + it * 256];
        }
        __syncthreads();
#pragma unroll 8
        for (int k = 0; k < KC; ++k) {
            float4 av = *reinterpret_cast<const float4*>(&sAT[k * 68 + ty * 4]);
            float4 wv = *reinterpret_cast<const float4*>(&sW[k * 64 + tx * 4]);
            acc[0][0] = fmaf(av.x, wv.x, acc[0][0]);
            acc[0][1] = fmaf(av.x, wv.y, acc[0][1]);
            acc[0][2] = fmaf(av.x, wv.z, acc[0][2]);
            acc[0][3] = fmaf(av.x, wv.w, acc[0][3]);
            acc[1][0] = fmaf(av.y, wv.x, acc[1][0]);
            acc[1][1] = fmaf(av.y, wv.y, acc[1][1]);
            acc[1][2] = fmaf(av.y, wv.z, acc[1][2]);
            acc[1][3] = fmaf(av.y, wv.w, acc[1][3]);
            acc[2][0] = fmaf(av.z, wv.x, acc[2][0]);
            acc[2][1] = fmaf(av.z, wv.y, acc[2][1]);
            acc[2][2] = fmaf(av.z, wv.z, acc[2][2]);
            acc[2][3] = fmaf(av.z, wv.w, acc[2][3]);
            acc[3][0] = fmaf(av.w, wv.x, acc[3][0]);
            acc[3][1] = fmaf(av.w, wv.y, acc[3][1]);
            acc[3][2] = fmaf(av.w, wv.z, acc[3][2]);
            acc[3][3] = fmaf(av.w, wv.w, acc[3][3]);
        }
        __syncthreads();
    }
#pragma unroll
    for (int i = 0; i < 4; ++i) {
        int r = row0 + ty * 4 + i;
        if (r < NN) {
            float s = scale ? scale[r] : 1.0f;
            float4 o = {acc[i][0] * s, acc[i][1] * s, acc[i][2] * s, acc[i][3] * s};
            if (OUT_BF16) {
                ushort4 h = {f2bf(o.x), f2bf(o.y), f2bf(o.z), f2bf(o.w)};
                *reinterpret_cast<ushort4*>((unsigned short*)Xout + (size_t)r * 64 + tx * 4) = h;
            } else {
                *reinterpret_cast<float4*>((float*)Xout + (size_t)r * 64 + tx * 4) = o;
            }
        }
    }
}

// ---- pull aggregation with optional fused next-layer projection ------------
// r4 gather core (8 groups x 8 cols, uint4 loads, f32 accum, best measured;
// remainder handling restored to r4's exact form — r11's refactor advanced i
// past unprocessed neighbors and dropped up to 7 per row).
// PROJ: after the xor-butterfly reduce (full row sum in every lane), fuse the
// next layer's input projection x = dout_is[n]*(h@Wn): group-0 lanes publish
// the 64 h values to LDS (same-wave write->read), then all 64 lanes each
// compute one output column against Wn staged in LDS and store bf16 to
// Xh_out. Absorbs the 3 proj<64> kernels into the BW-bound gathers.
template <bool SSCALE, bool PROJ>
__global__ __launch_bounds__(256) void gather8_bf16_kernel(
    const int* __restrict__ row_start, const int* __restrict__ csr_src,
    const unsigned short* __restrict__ Xh_in, const float* __restrict__ din_is,
    const float* __restrict__ sscale,
    const float* __restrict__ b, float* __restrict__ out,
    int ldo, int coff, int relu,
    const float* __restrict__ Wnext,      // 64x64 row-major (PROJ)
    const float* __restrict__ xscale,     // dout_is (PROJ)
    unsigned short* __restrict__ Xh_out) {
    __shared__ float sW[PROJ ? 64 * 64 : 1];
    __shared__ float sH[PROJ ? 4 * 64 : 1];

    if (PROJ) {
        const float4* ws = reinterpret_cast<const float4*>(Wnext);
        float4* wd = reinterpret_cast<float4*>(sW);
#pragma unroll
        for (int it = 0; it < 4; ++it) wd[threadIdx.x + it * 256] = ws[threadIdx.x + it * 256];
        __syncthreads();
    }

    const int wid = threadIdx.x >> 6;
    const int n = blockIdx.x * 4 + wid;       // grid is exactly NN/4: no guard
    const int lane = threadIdx.x & 63;
    const int g = lane >> 3;              // neighbor group 0..7
    const int c8 = (lane & 7) << 3;       // cols c8..c8+7
    const int s0 = row_start[n], s1 = row_start[n + 1];
    float a[8] = {};
    int i = s0;
    // 16 neighbors/iter: 2 independent 16B row loads in flight per lane
    for (; i + 16 <= s1; i += 16) {
        int ia = csr_src[i + g];
        int ib = csr_src[i + 8 + g];
        uint4 va = *reinterpret_cast<const uint4*>(Xh_in + (size_t)ia * 64 + c8);
        uint4 vb = *reinterpret_cast<const uint4*>(Xh_in + (size_t)ib * 64 + c8);
        float wa = SSCALE ? sscale[ia] : 1.0f;
        float wb = SSCALE ? sscale[ib] : 1.0f;
        {
            unsigned d0 = va.x, d1 = va.y, d2 = va.z, d3 = va.w;
            a[0] = fmaf(__uint_as_float(d0 << 16), wa, a[0]);
            a[1] = fmaf(__uint_as_float(d0 & 0xFFFF0000u), wa, a[1]);
            a[2] = fmaf(__uint_as_float(d1 << 16), wa, a[2]);
            a[3] = fmaf(__uint_as_float(d1 & 0xFFFF0000u), wa, a[3]);
            a[4] = fmaf(__uint_as_float(d2 << 16), wa, a[4]);
            a[5] = fmaf(__uint_as_float(d2 & 0xFFFF0000u), wa, a[5]);
            a[6] = fmaf(__uint_as_float(d3 << 16), wa, a[6]);
            a[7] = fmaf(__uint_as_float(d3 & 0xFFFF0000u), wa, a[7]);
        }
        {
            unsigned d0 = vb.x, d1 = vb.y, d2 = vb.z, d3 = vb.w;
            a[0] = fmaf(__uint_as_float(d0 << 16), wb, a[0]);
            a[1] = fmaf(__uint_as_float(d0 & 0xFFFF0000u), wb, a[1]);
            a[2] = fmaf(__uint_as_float(d1 << 16), wb, a[2]);
            a[3] = fmaf(__uint_as_float(d1 & 0xFFFF0000u), wb, a[3]);
            a[4] = fmaf(__uint_as_float(d2 << 16), wb, a[4]);
            a[5] = fmaf(__uint_as_float(d2 & 0xFFFF0000u), wb, a[5]);
            a[6] = fmaf(__uint_as_float(d3 << 16), wb, a[6]);
            a[7] = fmaf(__uint_as_float(d3 & 0xFFFF0000u), wb, a[7]);
        }
    }
    // 8 neighbors (at most one batch after the 16-loop) — r4 semantics
    if (i + 8 <= s1) {
        int ia = csr_src[i + g];
        uint4 va = *reinterpret_cast<const uint4*>(Xh_in + (size_t)ia * 64 + c8);
        float wa = SSCALE ? sscale[ia] : 1.0f;
        unsigned d0 = va.x, d1 = va.y, d2 = va.z, d3 = va.w;
        a[0] = fmaf(__uint_as_float(d0 << 16), wa, a[0]);
        a[1] = fmaf(__uint_as_float(d0 & 0xFFFF0000u), wa, a[1]);
        a[2] = fmaf(__uint_as_float(d1 << 16), wa, a[2]);
        a[3] = fmaf(__uint_as_float(d1 & 0xFFFF0000u), wa, a[3]);
        a[4] = fmaf(__uint_as_float(d2 << 16), wa, a[4]);
        a[5] = fmaf(__uint_as_float(d2 & 0xFFFF0000u), wa, a[5]);
        a[6] = fmaf(__uint_as_float(d3 << 16), wa, a[6]);
        a[7] = fmaf(__uint_as_float(d3 & 0xFFFF0000u), wa, a[7]);
        i += 8;
    }
    // <8 remaining, group-guarded
    if (i + g < s1) {
        int ia = csr_src[i + g];
        uint4 va = *reinterpret_cast<const uint4*>(Xh_in + (size_t)ia * 64 + c8);
        float wa = SSCALE ? sscale[ia] : 1.0f;
        unsigned d0 = va.x, d1 = va.y, d2 = va.z, d3 = va.w;
        a[0] = fmaf(__uint_as_float(d0 << 16), wa, a[0]);
        a[1] = fmaf(__uint_as_float(d0 & 0xFFFF0000u), wa, a[1]);
        a[2] = fmaf(__uint_as_float(d1 << 16), wa, a[2]);
        a[3] = fmaf(__uint_as_float(d1 & 0xFFFF0000u), wa, a[3]);
        a[4] = fmaf(__uint_as_float(d2 << 16), wa, a[4]);
        a[5] = fmaf(__uint_as_float(d2 & 0xFFFF0000u), wa, a[5]);
        a[6] = fmaf(__uint_as_float(d3 << 16), wa, a[6]);
        a[7] = fmaf(__uint_as_float(d3 & 0xFFFF0000u), wa, a[7]);
    }
    // xor-butterfly: ALL lanes end with the full row sum for their c8
#pragma unroll
    for (int off = 8; off < 64; off <<= 1) {
#pragma unroll
        for (int j = 0; j < 8; ++j) a[j] += __shfl_xor(a[j], off, 64);
    }
    // epilogue: h = relu(sum*din + b) (or sum + b for the tail)
    float h[8];
    if (relu) {
        float di = din_is[n];
#pragma unroll
        for (int j = 0; j < 8; ++j) h[j] = fmaxf(fmaf(a[j], di, b[c8 + j]), 0.0f);
    } else {
#pragma unroll
        for (int j = 0; j < 8; ++j) h[j] = a[j] + b[c8 + j];
    }
    if (g == 0) {
        float* op = out + (size_t)n * ldo + coff + c8;
        *reinterpret_cast<float4*>(op) = {h[0], h[1], h[2], h[3]};
        *reinterpret_cast<float4*>(op + 4) = {h[4], h[5], h[6], h[7]};
        if (PROJ) {
#pragma unroll
            for (int j = 0; j < 8; ++j) sH[wid * 64 + c8 + j] = h[j];
        }
    }
    if (PROJ) {
        // same-wave LDS write->read (compiler inserts the lgkmcnt dependency)
        float di = xscale[n];
        int c = lane;
        float acc = 0.0f;
#pragma unroll 8
        for (int k = 0; k < 64; ++k)
            acc = fmaf(sH[wid * 64 + k], sW[k * 64 + c], acc);
        Xh_out[(size_t)n * 64 + c] = f2bf(acc * di);
    }
}

extern "C" void kernel_launch(void* const* d_in, const int* in_sizes, int n_in,
                              void* d_out, int out_size, void* d_ws, size_t ws_size,
                              hipStream_t stream) {
    const float* feat  = (const float*)d_in[0];
    const int*   src   = (const int*)d_in[1];
    const int*   dst   = (const int*)d_in[2];
    const float* W[4]  = {(const float*)d_in[3], (const float*)d_in[5],
                          (const float*)d_in[7], (const float*)d_in[9]};
    const float* b[4]  = {(const float*)d_in[4], (const float*)d_in[6],
                          (const float*)d_in[8], (const float*)d_in[10]};
    const float* W_mlp = (const float*)d_in[11];
    const float* b_mlp = (const float*)d_in[12];
    float* out = (float*)d_out;

    // workspace layout:
    // C [NN*256 f]  (head transiently reused: dout_cnt [NN i] | cursor [NN i]
    //               | epos [NE i] — all dead before gather-0 writes C)
    // X [NN*64 f]   (= TWO bf16 ping-pong planes Xh_a, Xh_b of NN*64 ushorts)
    // dout_is [NN f] | din_is [NN f] |
    // row_start [NN+1 i] | partials [256 i] | csr_src [NE i]
    float* C        = (float*)d_ws;
    int*   dout_cnt = (int*)d_ws;            // NN
    int*   cursor   = dout_cnt + NN;         // NN (doubles as din_cnt)
    int*   epos     = cursor + NN;           // NE
    float* X        = C + (size_t)NN * 256;
    unsigned short* Xh_a = (unsigned short*)X;
    unsigned short* Xh_b = Xh_a + (size_t)NN * 64;
    float* dout_is  = X + (size_t)NN * 64;
    float* din_is   = dout_is + NN;
    int*   row_start = (int*)(din_is + NN);
    int*   partials  = row_start + NN + 1;
    int*   csr_src   = partials + 256;

    const int NBLK = (NN + 255) / 256;   // 196
    const int GBLK = (NN + 63) / 64;     // 782 (GEMM tiles)
    const int EBLK = (NE + 255) / 256;   // 3125
    const int DEGBLK = (NE + 2047) / 2048;  // 391 degree blocks (8 edges/thread)
    const int FBLK = GBLK + DEGBLK;      // 1173 fused blocks (391 degree @ bid%3==0)
    const int AGBLK = NN / 4;            // 12500, exact (50000/4)

    // zero dout_cnt + cursor (contiguous)
    hipMemsetAsync(dout_cnt, 0, 2 * NN * sizeof(int), stream);

    // fused: degree/cursor atomic pass overlapped with proj0 (unscaled feat@W0)
    fused_build_proj0_kernel<<<FBLK, 256, 0, stream>>>(feat, W[0], Xh_a,
                                                       src, dst, dout_cnt, cursor, epos);

    // row_start = exscan(cursor); fill is atomic-free
    scan_local_kernel<<<NBLK, 256, 0, stream>>>(cursor, row_start, partials);
    scan_partials_kernel<<<1, 256, 0, stream>>>(partials, NBLK, row_start);
    scan_add_norm_kernel<<<NBLK, 256, 0, stream>>>(row_start, partials, dout_cnt, cursor,
                                                   dout_is, din_is);
    csr_fill_kernel<<<EBLK, 256, 0, stream>>>(src, dst, row_start, epos, csr_src);

    // layer 0 gather (+fused x1-projection): reads Xh_a, writes C0 + Xh_b
    gather8_bf16_kernel<true, true><<<AGBLK, 256, 0, stream>>>(
        row_start, csr_src, Xh_a, din_is, dout_is, b[0], C, 256, 0, 1,
        W[1], dout_is, Xh_b);
    // layer 1 gather (+fused x2-projection): reads Xh_b, writes C1 + Xh_a
    gather8_bf16_kernel<false, true><<<AGBLK, 256, 0, stream>>>(
        row_start, csr_src, Xh_b, din_is, nullptr, b[1], C, 256, 64, 1,
        W[2], dout_is, Xh_a);
    // layer 2 gather (+fused x3-projection): reads Xh_a, writes C2 + Xh_b
    gather8_bf16_kernel<false, true><<<AGBLK, 256, 0, stream>>>(
        row_start, csr_src, Xh_a, din_is, nullptr, b[2], C, 256, 128, 1,
        W[3], dout_is, Xh_b);
    // layer 3 gather (no projection): reads Xh_b, writes C3
    gather8_bf16_kernel<false, false><<<AGBLK, 256, 0, stream>>>(
        row_start, csr_src, Xh_b, din_is, nullptr, b[3], C, 256, 192, 1,
        nullptr, nullptr, nullptr);

    // tail: P = C @ W_mlp as bf16 (project BEFORE the neighbor-sum; linear),
    // then out = b_mlp + segment_sum(P[src] -> dst)
    proj_kernel<256, true><<<GBLK, 256, 0, stream>>>(C, 256, W_mlp, nullptr, Xh_a);
    gather8_bf16_kernel<false, false><<<AGBLK, 256, 0, stream>>>(
        row_start, csr_src, Xh_a, nullptr, nullptr, b_mlp, out, 64, 0, 0,
        nullptr, nullptr, nullptr);
}